// Round 5
// baseline (1001.801 us; speedup 1.0000x reference)
//
#include <hip/hip_runtime.h>
#include <cstdint>
#include <math.h>

// Problem constants: B=32, TXT_T=256, MEL_T=1600, N_MEL=40
#define BB   32
#define LLEN 256
#define TLEN 1600
#define NC   40
#define NEGPADF (-1.0e12f)
#define NEGPADD (-1.0e12)
#define NBATCH 8            // DP columns per producer/consumer window

// Output layout (floats): mdn_loss[32] | alignment[32*1600*256] | lp[32*256*1600]
#define OFF_ALIGN 32
#define OFF_LP    (32 + (size_t)BB * TLEN * LLEN)

// Workspace (bytes): Ad double[32*256*80] | Kcd double[32*256] |
// lpTh float[32*1600*256] | path int[32*1600]   (~57.9 MB)
#define WSB_A    0
#define WSB_KC   (WSB_A + (size_t)BB * LLEN * 80 * 8)
#define WSB_LPT  (WSB_KC + (size_t)BB * LLEN * 8)
#define WSB_PATH (WSB_LPT + (size_t)BB * TLEN * LLEN * 4)

__device__ __forceinline__ int imin(int a, int b) { return a < b ? a : b; }

#define WAIT_LGKM0 0xC07F   // lgkmcnt(0) only, vmcnt untouched (validated R2/R3)

// Producer-side barrier: drain own LDS writes (lgkm only), then barrier.
// asm memory clobbers pin loads/stores inside their window.
__device__ __forceinline__ void bar_prod() {
  asm volatile("" ::: "memory");
  __builtin_amdgcn_s_waitcnt(WAIT_LGKM0);
  __builtin_amdgcn_s_barrier();
  asm volatile("" ::: "memory");
}
// Consumer-side barrier: no waitcnt (compiler inserts lgkm before uses).
__device__ __forceinline__ void bar_cons() {
  asm volatile("" ::: "memory");
  __builtin_amdgcn_s_barrier();
  asm volatile("" ::: "memory");
}

// ---------------------------------------------------------------------------
// K0 (f64): a1 = -0.5/C*invvar, a2 = (1/C)*mu*invvar,
//           Kc = -0.5/C*(sum mu^2*iv + sum lv)          [validated R2]
// ---------------------------------------------------------------------------
__global__ __launch_bounds__(256) void prep_kernel(
    const float* __restrict__ mu_logvar, double* __restrict__ A, double* __restrict__ Kc) {
  int row = blockIdx.x * 4 + (threadIdx.x >> 6);   // b*256 + l
  int lane = threadIdx.x & 63;
  const float* src = mu_logvar + (size_t)row * (2 * NC);
  double mu = 0.0, lv = 0.0, iv = 0.0, part = 0.0;
  if (lane < NC) {
    mu = (double)src[lane];
    lv = (double)src[NC + lane];
    iv = exp(-lv);
    part = mu * mu * iv + lv;
  }
  for (int m = 1; m < 64; m <<= 1) part += __shfl_xor(part, m, 64);
  const double s = -0.5 / (double)NC;
  if (lane < NC) {
    A[(size_t)row * 80 + lane]      = s * iv;
    A[(size_t)row * 80 + NC + lane] = (1.0 / (double)NC) * mu * iv;
  }
  if (lane == 0) Kc[row] = s * part;
}

// ---------------------------------------------------------------------------
// K1 (f64): lp[b][l][t] = Kc + sum_c (a1*z^2 + a2*z). Validated math (R2/R3).
// 17.4 KB LDS tile (16-l transpose groups) for occupancy; 64B-line stores.
// ---------------------------------------------------------------------------
__global__ __launch_bounds__(128) void lp_kernel(
    const float* __restrict__ z, const double* __restrict__ A,
    const double* __restrict__ Kc, float* __restrict__ out,
    float* __restrict__ lpTh) {
  int b  = blockIdx.z;
  int l0 = blockIdx.y * 32;
  int t0 = blockIdx.x * 128;
  int tid = threadIdx.x;
  int t = t0 + tid;
  int tv = imin(t, TLEN - 1);
  bool act = (t < TLEN);

  float* lp_out = out + OFF_LP;
  float* loS    = out + OFF_ALIGN;   // lo scratch [b][t][l], zeroed by finalize

  float zr[NC];
  const float* zb = z + (size_t)b * NC * TLEN;
  #pragma unroll
  for (int c = 0; c < NC; ++c) zr[c] = zb[(size_t)c * TLEN + tv];

  __shared__ __align__(16) double tile[128][17];   // 16 l's + pad
  const double* Ab = A + ((size_t)b * LLEN + l0) * 80;
  const double* Kb = Kc + (size_t)b * LLEN + l0;

  for (int g = 0; g < 2; ++g) {
    for (int j16 = 0; j16 < 16; ++j16) {
      int j = g * 16 + j16;
      const double* Ar = Ab + (size_t)j * 80;      // wave-uniform -> s_load
      double a0 = Kb[j], a1 = 0.0, a2 = 0.0, a3 = 0.0;
      #pragma unroll
      for (int c = 0; c < NC; c += 2) {
        double z0 = (double)zr[c], z1 = (double)zr[c + 1];
        a0 = fma(Ar[c],          z0 * z0, a0);
        a1 = fma(Ar[NC + c],     z0,      a1);
        a2 = fma(Ar[c + 1],      z1 * z1, a2);
        a3 = fma(Ar[NC + c + 1], z1,      a3);
      }
      double accd = (a0 + a2) + (a1 + a3);
      if (act) lp_out[((size_t)b * LLEN + l0 + j) * TLEN + t] = (float)accd;
      tile[tid][j16] = accd;
    }
    __syncthreads();
    #pragma unroll
    for (int p = 0; p < 4; ++p) {
      int idx = p * 128 + tid;       // 0..511
      int r = idx >> 2, c4 = idx & 3;
      int tr = t0 + r;
      if (tr < TLEN) {
        float h[4], lo[4];
        #pragma unroll
        for (int i = 0; i < 4; ++i) {
          double d = tile[r][c4 * 4 + i];
          float hh = (float)d;
          h[i] = hh;
          lo[i] = (float)(d - (double)hh);
        }
        size_t base = ((size_t)b * TLEN + tr) * LLEN + l0 + g * 16 + c4 * 4;
        *(float4*)(lpTh + base) = make_float4(h[0], h[1], h[2], h[3]);
        *(float4*)(loS + base)  = make_float4(lo[0], lo[1], lo[2], lo[3]);
      }
    }
    __syncthreads();
  }
}

// ---------------------------------------------------------------------------
// K2: producer/consumer DP. 64 blocks x 128 threads (2 waves).
// Wave 1 streams lp columns global->VGPR->LDS, 8-col batches, double-buffered,
// pipelined 2 batches deep. Wave 0 runs the DP purely from LDS (validated
// R3 math). Raw barrier per window, lgkm-only drain: producer's future global
// loads stay in flight across barriers.
// ---------------------------------------------------------------------------
__global__ __launch_bounds__(128, 1) void dp_kernel(
    const float* __restrict__ lpTh, const float* outR,
    const int* __restrict__ tlen, const int* __restrict__ mlen,
    float* __restrict__ out, int* __restrict__ pathg) {
  int bid = blockIdx.x;
  bool is_beta = (bid >= BB);
  int b = is_beta ? bid - BB : bid;
  int tid = threadIdx.x;
  int lane = tid & 63;
  int wv = tid >> 6;                   // 0 = consumer, 1 = producer
  int tl = tlen[b];
  int ml = mlen[b];
  const float* lpb = lpTh + (size_t)b * TLEN * LLEN;
  const float* lob = outR + OFF_ALIGN + (size_t)b * TLEN * LLEN;
  int nint = (ml - 2 + NBATCH) / NBATCH;   // ceil((ml-1)/8) windows

  __shared__ __align__(16) float hbuf[2][NBATCH][LLEN];   // 16 KB
  __shared__ __align__(16) float lbuf[2][NBATCH][LLEN];   // 16 KB
  __shared__ uint32_t Dbits[LLEN][TLEN / 32];             // 51.2 KB

  if (wv == 1) {
    // ---------------- producer ----------------
    const float* ph = lpb + 4 * lane;
    const float* pl = lob + 4 * lane;
    float4 Ah[NBATCH], Al[NBATCH], Bh[NBATCH], Bl[NBATCH];
    auto ld_batch = [&](int w, float4* Dh, float4* Dl) {
      #pragma unroll
      for (int j = 0; j < NBATCH; ++j) {
        int c = imin(1 + NBATCH * w + j, TLEN - 1);
        Dh[j] = *(const float4*)(ph + (size_t)c * LLEN);
        if (is_beta) Dl[j] = *(const float4*)(pl + (size_t)c * LLEN);
      }
    };
    auto st_batch = [&](int w, float4* Dh, float4* Dl) {
      int s = w & 1;
      #pragma unroll
      for (int j = 0; j < NBATCH; ++j) {
        *(float4*)(&hbuf[s][j][4 * lane]) = Dh[j];
        if (is_beta) *(float4*)(&lbuf[s][j][4 * lane]) = Dl[j];
      }
    };
    ld_batch(0, Ah, Al);
    ld_batch(1, Bh, Bl);
    for (int w = 0; w < nint; w += 2) {
      st_batch(w, Ah, Al);
      bar_prod();
      ld_batch(w + 2, Ah, Al);          // in flight across next window
      if (w + 1 < nint) {
        st_batch(w + 1, Bh, Bl);
        bar_prod();
        ld_batch(w + 3, Bh, Bl);
      }
    }
  } else if (!is_beta) {
    // ---------------- consumer: forward logsumexp (f32) ----------------
    int rsrc = (lane + 63) & 63;
    float lp00 = lpb[0];
    float o0 = (lane == 0) ? lp00 : NEGPADF;
    float o1 = NEGPADF, o2 = NEGPADF, o3 = NEGPADF;
    float f0 = o0, f1 = o1, f2 = o2, f3 = o3;
    float q = __shfl(o3, rsrc, 64);
    int t = 1;
    for (int w = 0; w < nint; ++w) {
      bar_cons();
      int s = w & 1;
      #pragma unroll
      for (int j = 0; j < NBATCH; ++j, ++t) {
        float4 lp4 = *(const float4*)(&hbuf[s][j][4 * lane]);
        float p = (lane == 0) ? NEGPADF : q;
        float m0 = fmaxf(o0, p),  d0 = fabsf(o0 - p);
        float m1 = fmaxf(o1, o0), d1 = fabsf(o1 - o0);
        float m2 = fmaxf(o2, o1), d2 = fabsf(o2 - o1);
        float m3 = fmaxf(o3, o2), d3 = fabsf(o3 - o2);
        float n0 = m0 + 1e-7f + __logf(1.0f + __expf(-d0)) + lp4.x;
        float n1 = m1 + 1e-7f + __logf(1.0f + __expf(-d1)) + lp4.y;
        float n2 = m2 + 1e-7f + __logf(1.0f + __expf(-d2)) + lp4.z;
        float n3 = m3 + 1e-7f + __logf(1.0f + __expf(-d3)) + lp4.w;
        o0 = n0; o1 = n1; o2 = n2; o3 = n3;
        q = __shfl(o3, rsrc, 64);
        if (t == ml - 1) { f0 = o0; f1 = o1; f2 = o2; f3 = o3; }
      }
    }
    int fr = tl - 1;
    if (lane == (fr >> 2)) {
      int sx = fr & 3;
      float val = (sx == 0) ? f0 : (sx == 1) ? f1 : (sx == 2) ? f2 : f3;
      out[b] = -val / (float)ml;
    }
  } else {
    // ---------------- consumer: Viterbi max-DP (f64) + bits ----------------
    int rsrc = (lane + 63) & 63;
    double lp00 = (double)lpb[0] + (double)lob[0];
    double o0 = (lane == 0) ? lp00 : NEGPADD;
    double o1 = NEGPADD, o2 = NEGPADD, o3 = NEGPADD;
    uint32_t a0 = 0, a1 = (lane == 0) ? 1u : 0u, a2 = 0, a3 = 0;
    double q = __shfl(o3, rsrc, 64);
    int t = 1;
    for (int w = 0; w < nint; ++w) {
      bar_cons();
      int s = w & 1;
      #pragma unroll
      for (int j = 0; j < NBATCH; ++j, ++t) {
        float4 h4 = *(const float4*)(&hbuf[s][j][4 * lane]);
        float4 l4 = *(const float4*)(&lbuf[s][j][4 * lane]);
        double l0 = (double)h4.x + (double)l4.x;
        double l1 = (double)h4.y + (double)l4.y;
        double l2 = (double)h4.z + (double)l4.z;
        double l3 = (double)h4.w + (double)l4.w;
        double p = (lane == 0) ? NEGPADD : q;
        double n0 = fmax(o0, p)  + l0;
        double n1 = fmax(o1, o0) + l1;
        double n2 = fmax(o2, o1) + l2;
        double n3 = fmax(o3, o2) + l3;
        q = __shfl(n3, rsrc, 64);          // row 4i-1 (mod 256) new beta
        uint32_t bit = 1u << (t & 31);
        if (q  > n0) a0 |= bit;
        if (n0 > n1) a1 |= bit;
        if (n1 > n2) a2 |= bit;
        if (n2 > n3) a3 |= bit;
        o0 = n0; o1 = n1; o2 = n2; o3 = n3;
        if ((t & 31) == 31) {
          int wd = t >> 5;
          Dbits[4 * lane + 0][wd] = a0; a0 = 0;
          Dbits[4 * lane + 1][wd] = a1; a1 = 0;
          Dbits[4 * lane + 2][wd] = a2; a2 = 0;
          Dbits[4 * lane + 3][wd] = a3; a3 = 0;
        }
      }
    }
    int tend = nint * NBATCH;            // last processed t
    if ((tend & 31) != 31) {
      int wd = tend >> 5;
      Dbits[4 * lane + 0][wd] = a0;
      Dbits[4 * lane + 1][wd] = a1;
      Dbits[4 * lane + 2][wd] = a2;
      Dbits[4 * lane + 3][wd] = a3;
    }
    __builtin_amdgcn_s_waitcnt(WAIT_LGKM0);  // drain own-wave LDS writes

    // -------- literal backtrack (validated R2/R3) --------
    if (lane == 0) {
      int* pb = pathg + b * TLEN;
      int r = tl - 1;
      pb[ml - 1] = r;
      int curR = 1 << 30, curW = -1;
      uint32_t W = 0;
      for (int qq = ml - 2; qq >= 0; --qq) {
        int wd = qq >> 5;
        if (r >= 0 && (r != curR || wd != curW)) { W = Dbits[r][wd]; curR = r; curW = wd; }
        int g = (r >= 0) ? (int)((W >> (qq & 31)) & 1u) : 0;
        r -= g;
        pb[qq] = r;
      }
    }
  }
}

// ---------------------------------------------------------------------------
// K3: zero the alignment region (held lo-scratch) + scatter one-hots, fused.
// ---------------------------------------------------------------------------
__global__ __launch_bounds__(256) void finalize_kernel(
    const int* __restrict__ mlen, const int* __restrict__ pathg,
    float* __restrict__ out) {
  int b = blockIdx.y;
  int t0 = blockIdx.x * 8;
  float* al = out + OFF_ALIGN + (size_t)b * TLEN * LLEN;
  float4 z4 = make_float4(0.f, 0.f, 0.f, 0.f);
  #pragma unroll
  for (int p = 0; p < 2; ++p) {
    int idx = p * 256 + threadIdx.x;
    int r = idx >> 6, c4 = idx & 63;
    *(float4*)(al + (size_t)(t0 + r) * LLEN + c4 * 4) = z4;
  }
  __syncthreads();
  if (threadIdx.x < 8) {
    int t = t0 + threadIdx.x;
    int ml = mlen[b];
    if (t < ml) {
      int p = pathg[b * TLEN + t];
      if (p >= 0) al[(size_t)t * LLEN + p] = 1.0f;
    }
  }
}

extern "C" void kernel_launch(void* const* d_in, const int* in_sizes, int n_in,
                              void* d_out, int out_size, void* d_ws, size_t ws_size,
                              hipStream_t stream) {
  const float* mu_logvar = (const float*)d_in[0];
  const float* z         = (const float*)d_in[1];
  const int*   tlv       = (const int*)d_in[2];
  const int*   mlv       = (const int*)d_in[3];
  float* out = (float*)d_out;
  char*  wsb = (char*)d_ws;

  double* Ad   = (double*)(wsb + WSB_A);
  double* Kcd  = (double*)(wsb + WSB_KC);
  float*  lpTh = (float*)(wsb + WSB_LPT);
  int*    path = (int*)(wsb + WSB_PATH);

  prep_kernel<<<dim3(BB * LLEN / 4), 256, 0, stream>>>(mu_logvar, Ad, Kcd);
  lp_kernel<<<dim3(13, 8, BB), 128, 0, stream>>>(z, Ad, Kcd, out, lpTh);
  dp_kernel<<<dim3(2 * BB), 128, 0, stream>>>(lpTh, out, tlv, mlv, out, path);
  finalize_kernel<<<dim3(TLEN / 8, BB), 256, 0, stream>>>(mlv, path, out);
}

// Round 6
// 596.048 us; speedup vs baseline: 1.6807x; 1.6807x over previous
//
#include <hip/hip_runtime.h>
#include <cstdint>
#include <math.h>

// Problem constants: B=32, TXT_T=256, MEL_T=1600, N_MEL=40
#define BB   32
#define LLEN 256
#define TLEN 1600
#define NC   40
#define NEGPADF (-1.0e12f)
#define NEGPADD (-1.0e12)
#define NBATCH 8            // DP columns per window
#define NPROD  4            // producer waves
#define NBUF   2            // LDS column buffers

// Output layout (floats): mdn_loss[32] | alignment[32*1600*256] | lp[32*256*1600]
#define OFF_ALIGN 32
#define OFF_LP    (32 + (size_t)BB * TLEN * LLEN)

// Workspace (bytes): Ad double[32*256*80] | Kcd double[32*256] |
// lpTh float[32*1600*256] | path int[32*1600]   (~57.9 MB)
#define WSB_A    0
#define WSB_KC   (WSB_A + (size_t)BB * LLEN * 80 * 8)
#define WSB_LPT  (WSB_KC + (size_t)BB * LLEN * 8)
#define WSB_PATH (WSB_LPT + (size_t)BB * TLEN * LLEN * 4)

__device__ __forceinline__ int imin(int a, int b) { return a < b ? a : b; }

#define WAIT_LGKM0 0xC07F   // lgkmcnt(0) only, vmcnt untouched (validated R2/R3/R5)

// Barrier draining LDS ops only: producer's future global loads stay in flight.
__device__ __forceinline__ void bar_prod() {
  asm volatile("" ::: "memory");
  __builtin_amdgcn_s_waitcnt(WAIT_LGKM0);
  __builtin_amdgcn_s_barrier();
  asm volatile("" ::: "memory");
}
__device__ __forceinline__ void bar_cons() {
  asm volatile("" ::: "memory");
  __builtin_amdgcn_s_barrier();
  asm volatile("" ::: "memory");
}

// ---------------------------------------------------------------------------
// K0 (f64) [validated R2]
// ---------------------------------------------------------------------------
__global__ __launch_bounds__(256) void prep_kernel(
    const float* __restrict__ mu_logvar, double* __restrict__ A, double* __restrict__ Kc) {
  int row = blockIdx.x * 4 + (threadIdx.x >> 6);   // b*256 + l
  int lane = threadIdx.x & 63;
  const float* src = mu_logvar + (size_t)row * (2 * NC);
  double mu = 0.0, lv = 0.0, iv = 0.0, part = 0.0;
  if (lane < NC) {
    mu = (double)src[lane];
    lv = (double)src[NC + lane];
    iv = exp(-lv);
    part = mu * mu * iv + lv;
  }
  for (int m = 1; m < 64; m <<= 1) part += __shfl_xor(part, m, 64);
  const double s = -0.5 / (double)NC;
  if (lane < NC) {
    A[(size_t)row * 80 + lane]      = s * iv;
    A[(size_t)row * 80 + NC + lane] = (1.0 / (double)NC) * mu * iv;
  }
  if (lane == 0) Kc[row] = s * part;
}

// ---------------------------------------------------------------------------
// K1 (f64) [validated R2/R3/R5 math]: lp + hi/lo transposed copies.
// ---------------------------------------------------------------------------
__global__ __launch_bounds__(128) void lp_kernel(
    const float* __restrict__ z, const double* __restrict__ A,
    const double* __restrict__ Kc, float* __restrict__ out,
    float* __restrict__ lpTh) {
  int b  = blockIdx.z;
  int l0 = blockIdx.y * 32;
  int t0 = blockIdx.x * 128;
  int tid = threadIdx.x;
  int t = t0 + tid;
  int tv = imin(t, TLEN - 1);
  bool act = (t < TLEN);

  float* lp_out = out + OFF_LP;
  float* loS    = out + OFF_ALIGN;   // lo scratch [b][t][l], zeroed by finalize

  float zr[NC];
  const float* zb = z + (size_t)b * NC * TLEN;
  #pragma unroll
  for (int c = 0; c < NC; ++c) zr[c] = zb[(size_t)c * TLEN + tv];

  __shared__ __align__(16) double tile[128][17];
  const double* Ab = A + ((size_t)b * LLEN + l0) * 80;
  const double* Kb = Kc + (size_t)b * LLEN + l0;

  for (int g = 0; g < 2; ++g) {
    for (int j16 = 0; j16 < 16; ++j16) {
      int j = g * 16 + j16;
      const double* Ar = Ab + (size_t)j * 80;      // wave-uniform -> s_load
      double a0 = Kb[j], a1 = 0.0, a2 = 0.0, a3 = 0.0;
      #pragma unroll
      for (int c = 0; c < NC; c += 2) {
        double z0 = (double)zr[c], z1 = (double)zr[c + 1];
        a0 = fma(Ar[c],          z0 * z0, a0);
        a1 = fma(Ar[NC + c],     z0,      a1);
        a2 = fma(Ar[c + 1],      z1 * z1, a2);
        a3 = fma(Ar[NC + c + 1], z1,      a3);
      }
      double accd = (a0 + a2) + (a1 + a3);
      if (act) lp_out[((size_t)b * LLEN + l0 + j) * TLEN + t] = (float)accd;
      tile[tid][j16] = accd;
    }
    __syncthreads();
    #pragma unroll
    for (int p = 0; p < 4; ++p) {
      int idx = p * 128 + tid;
      int r = idx >> 2, c4 = idx & 3;
      int tr = t0 + r;
      if (tr < TLEN) {
        float h[4], lo[4];
        #pragma unroll
        for (int i = 0; i < 4; ++i) {
          double d = tile[r][c4 * 4 + i];
          float hh = (float)d;
          h[i] = hh;
          lo[i] = (float)(d - (double)hh);
        }
        size_t base = ((size_t)b * TLEN + tr) * LLEN + l0 + g * 16 + c4 * 4;
        *(float4*)(lpTh + base) = make_float4(h[0], h[1], h[2], h[3]);
        *(float4*)(loS + base)  = make_float4(lo[0], lo[1], lo[2], lo[3]);
      }
    }
    __syncthreads();
  }
}

// ---------------------------------------------------------------------------
// K2: DP, 64 blocks x 320 threads (1 consumer wave + 4 producer waves).
// Producer q owns windows w ≡ q (mod 4): holds ONE 8-column window in regs
// (64 VGPRs — under the compiler's demotion threshold per R2/R3/R5 evidence),
// stores it to LDS during window w-1, then immediately issues w+4 (loads in
// flight ~3 windows ≈ 1500+ cyc). Beta producers pre-add hi+lo into f64.
// Consumer = validated R5 step math, LDS-only reads.
// ---------------------------------------------------------------------------
__global__ __launch_bounds__(320, 1) void dp_kernel(
    const float* __restrict__ lpTh, const float* outR,
    const int* __restrict__ tlen, const int* __restrict__ mlen,
    float* __restrict__ out, int* __restrict__ pathg) {
  int bid = blockIdx.x;
  bool is_beta = (bid >= BB);
  int b = is_beta ? bid - BB : bid;
  int tid = threadIdx.x;
  int lane = tid & 63;
  int wv = tid >> 6;                   // 0 = consumer, 1..4 = producers
  int tl = tlen[b];
  int ml = mlen[b];
  const float* lpb = lpTh + (size_t)b * TLEN * LLEN;
  const float* lob = outR + OFF_ALIGN + (size_t)b * TLEN * LLEN;
  int nint = (ml - 2 + NBATCH) / NBATCH;   // windows of 8 steps

  __shared__ double   bufd[NBUF][NBATCH][4][64];   // beta cols (f64), 32 KB
  __shared__ float    buff[NBUF][NBATCH][LLEN];    // alpha cols (f32), 16 KB
  __shared__ uint32_t Dbits[LLEN][TLEN / 32];      // 51.2 KB

  if (wv >= 1) {
    // ---------------- producers ----------------
    int q = wv - 1;
    const float* ph = lpb + 4 * lane;
    const float* pl = lob + 4 * lane;
    float4 vh[NBATCH], vl[NBATCH];
    auto issue = [&](int w) {
      #pragma unroll
      for (int j = 0; j < NBATCH; ++j) {
        int c = imin(1 + NBATCH * w + j, TLEN - 1);
        vh[j] = *(const float4*)(ph + (size_t)c * LLEN);
        if (is_beta) vl[j] = *(const float4*)(pl + (size_t)c * LLEN);
      }
    };
    auto store = [&](int w) {
      int s = w % NBUF;
      if (is_beta) {
        #pragma unroll
        for (int j = 0; j < NBATCH; ++j) {
          bufd[s][j][0][lane] = (double)vh[j].x + (double)vl[j].x;
          bufd[s][j][1][lane] = (double)vh[j].y + (double)vl[j].y;
          bufd[s][j][2][lane] = (double)vh[j].z + (double)vl[j].z;
          bufd[s][j][3][lane] = (double)vh[j].w + (double)vl[j].w;
        }
      } else {
        #pragma unroll
        for (int j = 0; j < NBATCH; ++j)
          *(float4*)(&buff[s][j][4 * lane]) = vh[j];
      }
    };
    if (q < nint) issue(q);
    if (q == 0) {                    // window 0 must be in LDS before barrier 0
      store(0);
      if (NPROD < nint) issue(NPROD);
    }
    for (int w = 0; w < nint; ++w) {
      bar_prod();
      int nw = w + 1;
      if (nw < nint && (nw % NPROD) == q) {
        store(nw);                   // vmcnt wait: only own batch outstanding
        int fw = nw + NPROD;
        if (fw < nint) issue(fw);
      }
    }
  } else if (!is_beta) {
    // ---------------- consumer: forward logsumexp (f32) [validated R5] -----
    int rsrc = (lane + 63) & 63;
    float lp00 = lpb[0];
    float o0 = (lane == 0) ? lp00 : NEGPADF;
    float o1 = NEGPADF, o2 = NEGPADF, o3 = NEGPADF;
    float f0 = o0, f1 = o1, f2 = o2, f3 = o3;
    float q = __shfl(o3, rsrc, 64);
    int t = 1;
    for (int w = 0; w < nint; ++w) {
      bar_cons();
      int s = w % NBUF;
      #pragma unroll
      for (int j = 0; j < NBATCH; ++j, ++t) {
        float4 lp4 = *(const float4*)(&buff[s][j][4 * lane]);
        float p = (lane == 0) ? NEGPADF : q;
        float m0 = fmaxf(o0, p),  d0 = fabsf(o0 - p);
        float m1 = fmaxf(o1, o0), d1 = fabsf(o1 - o0);
        float m2 = fmaxf(o2, o1), d2 = fabsf(o2 - o1);
        float m3 = fmaxf(o3, o2), d3 = fabsf(o3 - o2);
        float n0 = m0 + 1e-7f + __logf(1.0f + __expf(-d0)) + lp4.x;
        float n1 = m1 + 1e-7f + __logf(1.0f + __expf(-d1)) + lp4.y;
        float n2 = m2 + 1e-7f + __logf(1.0f + __expf(-d2)) + lp4.z;
        float n3 = m3 + 1e-7f + __logf(1.0f + __expf(-d3)) + lp4.w;
        o0 = n0; o1 = n1; o2 = n2; o3 = n3;
        q = __shfl(o3, rsrc, 64);
        if (t == ml - 1) { f0 = o0; f1 = o1; f2 = o2; f3 = o3; }
      }
    }
    int fr = tl - 1;
    if (lane == (fr >> 2)) {
      int sx = fr & 3;
      float val = (sx == 0) ? f0 : (sx == 1) ? f1 : (sx == 2) ? f2 : f3;
      out[b] = -val / (float)ml;
    }
  } else {
    // ---------------- consumer: Viterbi max-DP (f64) [validated R5] --------
    int rsrc = (lane + 63) & 63;
    double lp00 = (double)lpb[0] + (double)lob[0];
    double o0 = (lane == 0) ? lp00 : NEGPADD;
    double o1 = NEGPADD, o2 = NEGPADD, o3 = NEGPADD;
    uint32_t a0 = 0, a1 = (lane == 0) ? 1u : 0u, a2 = 0, a3 = 0;
    double q = __shfl(o3, rsrc, 64);
    int t = 1;
    for (int w = 0; w < nint; ++w) {
      bar_cons();
      int s = w % NBUF;
      #pragma unroll
      for (int j = 0; j < NBATCH; ++j, ++t) {
        double l0 = bufd[s][j][0][lane];
        double l1 = bufd[s][j][1][lane];
        double l2 = bufd[s][j][2][lane];
        double l3 = bufd[s][j][3][lane];
        double p = (lane == 0) ? NEGPADD : q;
        double n0 = fmax(o0, p)  + l0;
        double n1 = fmax(o1, o0) + l1;
        double n2 = fmax(o2, o1) + l2;
        double n3 = fmax(o3, o2) + l3;
        q = __shfl(n3, rsrc, 64);          // row 4i-1 (mod 256) new beta
        uint32_t bit = 1u << (t & 31);
        if (q  > n0) a0 |= bit;
        if (n0 > n1) a1 |= bit;
        if (n1 > n2) a2 |= bit;
        if (n2 > n3) a3 |= bit;
        o0 = n0; o1 = n1; o2 = n2; o3 = n3;
        if ((t & 31) == 31) {
          int wd = t >> 5;
          Dbits[4 * lane + 0][wd] = a0; a0 = 0;
          Dbits[4 * lane + 1][wd] = a1; a1 = 0;
          Dbits[4 * lane + 2][wd] = a2; a2 = 0;
          Dbits[4 * lane + 3][wd] = a3; a3 = 0;
        }
      }
    }
    int tend = nint * NBATCH;            // last processed t
    if ((tend & 31) != 31) {
      int wd = tend >> 5;
      Dbits[4 * lane + 0][wd] = a0;
      Dbits[4 * lane + 1][wd] = a1;
      Dbits[4 * lane + 2][wd] = a2;
      Dbits[4 * lane + 3][wd] = a3;
    }
    __builtin_amdgcn_s_waitcnt(WAIT_LGKM0);  // drain own-wave LDS writes

    // -------- literal backtrack [validated R2/R3/R5] --------
    if (lane == 0) {
      int* pb = pathg + b * TLEN;
      int r = tl - 1;
      pb[ml - 1] = r;
      int curR = 1 << 30, curW = -1;
      uint32_t W = 0;
      for (int qq = ml - 2; qq >= 0; --qq) {
        int wd = qq >> 5;
        if (r >= 0 && (r != curR || wd != curW)) { W = Dbits[r][wd]; curR = r; curW = wd; }
        int g = (r >= 0) ? (int)((W >> (qq & 31)) & 1u) : 0;
        r -= g;
        pb[qq] = r;
      }
    }
  }
}

// ---------------------------------------------------------------------------
// K3: zero alignment region (held lo-scratch) + scatter one-hots [validated R5]
// ---------------------------------------------------------------------------
__global__ __launch_bounds__(256) void finalize_kernel(
    const int* __restrict__ mlen, const int* __restrict__ pathg,
    float* __restrict__ out) {
  int b = blockIdx.y;
  int t0 = blockIdx.x * 8;
  float* al = out + OFF_ALIGN + (size_t)b * TLEN * LLEN;
  float4 z4 = make_float4(0.f, 0.f, 0.f, 0.f);
  #pragma unroll
  for (int p = 0; p < 2; ++p) {
    int idx = p * 256 + threadIdx.x;
    int r = idx >> 6, c4 = idx & 63;
    *(float4*)(al + (size_t)(t0 + r) * LLEN + c4 * 4) = z4;
  }
  __syncthreads();
  if (threadIdx.x < 8) {
    int t = t0 + threadIdx.x;
    int ml = mlen[b];
    if (t < ml) {
      int p = pathg[b * TLEN + t];
      if (p >= 0) al[(size_t)t * LLEN + p] = 1.0f;
    }
  }
}

extern "C" void kernel_launch(void* const* d_in, const int* in_sizes, int n_in,
                              void* d_out, int out_size, void* d_ws, size_t ws_size,
                              hipStream_t stream) {
  const float* mu_logvar = (const float*)d_in[0];
  const float* z         = (const float*)d_in[1];
  const int*   tlv       = (const int*)d_in[2];
  const int*   mlv       = (const int*)d_in[3];
  float* out = (float*)d_out;
  char*  wsb = (char*)d_ws;

  double* Ad   = (double*)(wsb + WSB_A);
  double* Kcd  = (double*)(wsb + WSB_KC);
  float*  lpTh = (float*)(wsb + WSB_LPT);
  int*    path = (int*)(wsb + WSB_PATH);

  prep_kernel<<<dim3(BB * LLEN / 4), 256, 0, stream>>>(mu_logvar, Ad, Kcd);
  lp_kernel<<<dim3(13, 8, BB), 128, 0, stream>>>(z, Ad, Kcd, out, lpTh);
  dp_kernel<<<dim3(2 * BB), 320, 0, stream>>>(lpTh, out, tlv, mlv, out, path);
  finalize_kernel<<<dim3(TLEN / 8, BB), 256, 0, stream>>>(mlv, path, out);
}

// Round 7
// 560.959 us; speedup vs baseline: 1.7859x; 1.0626x over previous
//
#include <hip/hip_runtime.h>
#include <cstdint>
#include <math.h>

// Problem constants: B=32, TXT_T=256, MEL_T=1600, N_MEL=40
#define BB   32
#define LLEN 256
#define TLEN 1600
#define NC   40
#define NEGPADF (-1.0e12f)
#define NEGPADD (-1.0e12)
#define NBATCH 8            // DP columns per window
#define NPROD  4            // producer waves
#define NBUF   2            // LDS column buffers

// Output layout (floats): mdn_loss[32] | alignment[32*1600*256] | lp[32*256*1600]
#define OFF_ALIGN 32
#define OFF_LP    (32 + (size_t)BB * TLEN * LLEN)

// Workspace (bytes): Ad double[32*256*80] | Kcd double[32*256] |
// lpTh float[32*1600*256] | path int[32*1600]   (~57.9 MB)
#define WSB_A    0
#define WSB_KC   (WSB_A + (size_t)BB * LLEN * 80 * 8)
#define WSB_LPT  (WSB_KC + (size_t)BB * LLEN * 8)
#define WSB_PATH (WSB_LPT + (size_t)BB * TLEN * LLEN * 4)

__device__ __forceinline__ int imin(int a, int b) { return a < b ? a : b; }

#define WAIT_LGKM0 0xC07F   // lgkmcnt(0) only, vmcnt untouched (validated R2-R6)

// Barrier draining LDS ops only: producer's future global loads stay in flight.
__device__ __forceinline__ void bar_prod() {
  asm volatile("" ::: "memory");
  __builtin_amdgcn_s_waitcnt(WAIT_LGKM0);
  __builtin_amdgcn_s_barrier();
  asm volatile("" ::: "memory");
}
__device__ __forceinline__ void bar_cons() {
  asm volatile("" ::: "memory");
  __builtin_amdgcn_s_barrier();
  asm volatile("" ::: "memory");
}

// DPP wave-rotate-right-1: lane i <- lane i-1, lane 0 <- lane 63. VALU-only
// (~4-8 cyc) vs ds_bpermute (~120 cyc) — removes LDS hw from the DP cycle.
__device__ __forceinline__ int rot1_i32(int x) {
  return __builtin_amdgcn_mov_dpp(x, 0x13C /*wave_ror:1*/, 0xF, 0xF, true);
}
__device__ __forceinline__ float rot1_f32(float x) {
  return __int_as_float(rot1_i32(__float_as_int(x)));
}
__device__ __forceinline__ double rot1_f64(double x) {
  long long v = __double_as_longlong(x);
  int lo = rot1_i32((int)(v & 0xffffffffLL));
  int hi = rot1_i32((int)(v >> 32));
  return __longlong_as_double(((long long)hi << 32) | (unsigned long long)(unsigned int)lo);
}

// ---------------------------------------------------------------------------
// K0 (f64) [validated R2]
// ---------------------------------------------------------------------------
__global__ __launch_bounds__(256) void prep_kernel(
    const float* __restrict__ mu_logvar, double* __restrict__ A, double* __restrict__ Kc) {
  int row = blockIdx.x * 4 + (threadIdx.x >> 6);   // b*256 + l
  int lane = threadIdx.x & 63;
  const float* src = mu_logvar + (size_t)row * (2 * NC);
  double mu = 0.0, lv = 0.0, iv = 0.0, part = 0.0;
  if (lane < NC) {
    mu = (double)src[lane];
    lv = (double)src[NC + lane];
    iv = exp(-lv);
    part = mu * mu * iv + lv;
  }
  for (int m = 1; m < 64; m <<= 1) part += __shfl_xor(part, m, 64);
  const double s = -0.5 / (double)NC;
  if (lane < NC) {
    A[(size_t)row * 80 + lane]      = s * iv;
    A[(size_t)row * 80 + NC + lane] = (1.0 / (double)NC) * mu * iv;
  }
  if (lane == 0) Kc[row] = s * part;
}

// ---------------------------------------------------------------------------
// K1 (f64) [validated R2/R3/R5/R6 math]: lp + hi/lo transposed copies.
// ---------------------------------------------------------------------------
__global__ __launch_bounds__(128) void lp_kernel(
    const float* __restrict__ z, const double* __restrict__ A,
    const double* __restrict__ Kc, float* __restrict__ out,
    float* __restrict__ lpTh) {
  int b  = blockIdx.z;
  int l0 = blockIdx.y * 32;
  int t0 = blockIdx.x * 128;
  int tid = threadIdx.x;
  int t = t0 + tid;
  int tv = imin(t, TLEN - 1);
  bool act = (t < TLEN);

  float* lp_out = out + OFF_LP;
  float* loS    = out + OFF_ALIGN;   // lo scratch [b][t][l], zeroed by finalize

  float zr[NC];
  const float* zb = z + (size_t)b * NC * TLEN;
  #pragma unroll
  for (int c = 0; c < NC; ++c) zr[c] = zb[(size_t)c * TLEN + tv];

  __shared__ __align__(16) double tile[128][17];
  const double* Ab = A + ((size_t)b * LLEN + l0) * 80;
  const double* Kb = Kc + (size_t)b * LLEN + l0;

  for (int g = 0; g < 2; ++g) {
    for (int j16 = 0; j16 < 16; ++j16) {
      int j = g * 16 + j16;
      const double* Ar = Ab + (size_t)j * 80;      // wave-uniform -> s_load
      double a0 = Kb[j], a1 = 0.0, a2 = 0.0, a3 = 0.0;
      #pragma unroll
      for (int c = 0; c < NC; c += 2) {
        double z0 = (double)zr[c], z1 = (double)zr[c + 1];
        a0 = fma(Ar[c],          z0 * z0, a0);
        a1 = fma(Ar[NC + c],     z0,      a1);
        a2 = fma(Ar[c + 1],      z1 * z1, a2);
        a3 = fma(Ar[NC + c + 1], z1,      a3);
      }
      double accd = (a0 + a2) + (a1 + a3);
      if (act) lp_out[((size_t)b * LLEN + l0 + j) * TLEN + t] = (float)accd;
      tile[tid][j16] = accd;
    }
    __syncthreads();
    #pragma unroll
    for (int p = 0; p < 4; ++p) {
      int idx = p * 128 + tid;
      int r = idx >> 2, c4 = idx & 3;
      int tr = t0 + r;
      if (tr < TLEN) {
        float h[4], lo[4];
        #pragma unroll
        for (int i = 0; i < 4; ++i) {
          double d = tile[r][c4 * 4 + i];
          float hh = (float)d;
          h[i] = hh;
          lo[i] = (float)(d - (double)hh);
        }
        size_t base = ((size_t)b * TLEN + tr) * LLEN + l0 + g * 16 + c4 * 4;
        *(float4*)(lpTh + base) = make_float4(h[0], h[1], h[2], h[3]);
        *(float4*)(loS + base)  = make_float4(lo[0], lo[1], lo[2], lo[3]);
      }
    }
    __syncthreads();
  }
}

// ---------------------------------------------------------------------------
// K2: DP, 64 blocks x 320 threads (1 consumer + 4 producer waves) [R6 struct].
// R7 changes: DPP rotate replaces __shfl (LDS hw off the DP critical cycle);
// plane LDS layout [j][row][lane] for conflict-free ds_read_b64/b32;
// Dbits tail-flush OOB guard (ml>=1594 landmine).
// ---------------------------------------------------------------------------
__global__ __launch_bounds__(320, 1) void dp_kernel(
    const float* __restrict__ lpTh, const float* outR,
    const int* __restrict__ tlen, const int* __restrict__ mlen,
    float* __restrict__ out, int* __restrict__ pathg) {
  int bid = blockIdx.x;
  bool is_beta = (bid >= BB);
  int b = is_beta ? bid - BB : bid;
  int tid = threadIdx.x;
  int lane = tid & 63;
  int wv = tid >> 6;                   // 0 = consumer, 1..4 = producers
  int tl = tlen[b];
  int ml = mlen[b];
  const float* lpb = lpTh + (size_t)b * TLEN * LLEN;
  const float* lob = outR + OFF_ALIGN + (size_t)b * TLEN * LLEN;
  int nint = (ml - 2 + NBATCH) / NBATCH;   // windows of 8 steps

  __shared__ double   bufd[NBUF][NBATCH][4][64];   // beta cols (f64), 32 KB
  __shared__ float    bufa[NBUF][NBATCH][4][64];   // alpha cols (f32), 8 KB
  __shared__ uint32_t Dbits[LLEN][TLEN / 32];      // 51.2 KB

  if (wv >= 1) {
    // ---------------- producers [R6-validated schedule] ----------------
    int q = wv - 1;
    const float* ph = lpb + 4 * lane;
    const float* pl = lob + 4 * lane;
    float4 vh[NBATCH], vl[NBATCH];
    auto issue = [&](int w) {
      #pragma unroll
      for (int j = 0; j < NBATCH; ++j) {
        int c = imin(1 + NBATCH * w + j, TLEN - 1);
        vh[j] = *(const float4*)(ph + (size_t)c * LLEN);
        if (is_beta) vl[j] = *(const float4*)(pl + (size_t)c * LLEN);
      }
    };
    auto store = [&](int w) {
      int s = w % NBUF;
      if (is_beta) {
        #pragma unroll
        for (int j = 0; j < NBATCH; ++j) {
          bufd[s][j][0][lane] = (double)vh[j].x + (double)vl[j].x;
          bufd[s][j][1][lane] = (double)vh[j].y + (double)vl[j].y;
          bufd[s][j][2][lane] = (double)vh[j].z + (double)vl[j].z;
          bufd[s][j][3][lane] = (double)vh[j].w + (double)vl[j].w;
        }
      } else {
        #pragma unroll
        for (int j = 0; j < NBATCH; ++j) {
          bufa[s][j][0][lane] = vh[j].x;
          bufa[s][j][1][lane] = vh[j].y;
          bufa[s][j][2][lane] = vh[j].z;
          bufa[s][j][3][lane] = vh[j].w;
        }
      }
    };
    if (q < nint) issue(q);
    if (q == 0) {                    // window 0 in LDS before barrier 0
      store(0);
      if (NPROD < nint) issue(NPROD);
    }
    for (int w = 0; w < nint; ++w) {
      bar_prod();
      int nw = w + 1;
      if (nw < nint && (nw % NPROD) == q) {
        store(nw);                   // vmcnt wait: only own batch outstanding
        int fw = nw + NPROD;
        if (fw < nint) issue(fw);
      }
    }
  } else if (!is_beta) {
    // ---------------- consumer: forward logsumexp (f32) --------------------
    float lp00 = lpb[0];
    float o0 = (lane == 0) ? lp00 : NEGPADF;
    float o1 = NEGPADF, o2 = NEGPADF, o3 = NEGPADF;
    float f0 = o0, f1 = o1, f2 = o2, f3 = o3;
    float q = rot1_f32(o3);
    int t = 1;
    for (int w = 0; w < nint; ++w) {
      bar_cons();
      int s = w % NBUF;
      #pragma unroll
      for (int j = 0; j < NBATCH; ++j, ++t) {
        float l0 = bufa[s][j][0][lane];
        float l1 = bufa[s][j][1][lane];
        float l2 = bufa[s][j][2][lane];
        float l3 = bufa[s][j][3][lane];
        float p = (lane == 0) ? NEGPADF : q;
        float m0 = fmaxf(o0, p),  d0 = fabsf(o0 - p);
        float m1 = fmaxf(o1, o0), d1 = fabsf(o1 - o0);
        float m2 = fmaxf(o2, o1), d2 = fabsf(o2 - o1);
        float m3 = fmaxf(o3, o2), d3 = fabsf(o3 - o2);
        float n0 = m0 + 1e-7f + __logf(1.0f + __expf(-d0)) + l0;
        float n1 = m1 + 1e-7f + __logf(1.0f + __expf(-d1)) + l1;
        float n2 = m2 + 1e-7f + __logf(1.0f + __expf(-d2)) + l2;
        float n3 = m3 + 1e-7f + __logf(1.0f + __expf(-d3)) + l3;
        o0 = n0; o1 = n1; o2 = n2; o3 = n3;
        q = rot1_f32(o3);
        if (t == ml - 1) { f0 = o0; f1 = o1; f2 = o2; f3 = o3; }
      }
    }
    int fr = tl - 1;
    if (lane == (fr >> 2)) {
      int sx = fr & 3;
      float val = (sx == 0) ? f0 : (sx == 1) ? f1 : (sx == 2) ? f2 : f3;
      out[b] = -val / (float)ml;
    }
  } else {
    // ---------------- consumer: Viterbi max-DP (f64) -----------------------
    double lp00 = (double)lpb[0] + (double)lob[0];
    double o0 = (lane == 0) ? lp00 : NEGPADD;
    double o1 = NEGPADD, o2 = NEGPADD, o3 = NEGPADD;
    uint32_t a0 = 0, a1 = (lane == 0) ? 1u : 0u, a2 = 0, a3 = 0;
    double q = rot1_f64(o3);
    int t = 1;
    for (int w = 0; w < nint; ++w) {
      bar_cons();
      int s = w % NBUF;
      #pragma unroll
      for (int j = 0; j < NBATCH; ++j, ++t) {
        double l0 = bufd[s][j][0][lane];
        double l1 = bufd[s][j][1][lane];
        double l2 = bufd[s][j][2][lane];
        double l3 = bufd[s][j][3][lane];
        double p = (lane == 0) ? NEGPADD : q;
        double n0 = fmax(o0, p)  + l0;
        double n1 = fmax(o1, o0) + l1;
        double n2 = fmax(o2, o1) + l2;
        double n3 = fmax(o3, o2) + l3;
        q = rot1_f64(n3);                 // row 4i-1 (mod 256) new beta
        uint32_t bit = 1u << (t & 31);
        if (q  > n0) a0 |= bit;
        if (n0 > n1) a1 |= bit;
        if (n1 > n2) a2 |= bit;
        if (n2 > n3) a3 |= bit;
        o0 = n0; o1 = n1; o2 = n2; o3 = n3;
        if ((t & 31) == 31) {
          int wd = t >> 5;
          Dbits[4 * lane + 0][wd] = a0; a0 = 0;
          Dbits[4 * lane + 1][wd] = a1; a1 = 0;
          Dbits[4 * lane + 2][wd] = a2; a2 = 0;
          Dbits[4 * lane + 3][wd] = a3; a3 = 0;
        }
      }
    }
    int tend = nint * NBATCH;            // last processed t
    int wd = tend >> 5;
    if ((tend & 31) != 31 && wd < TLEN / 32) {  // OOB guard: ml>=1594 landmine
      Dbits[4 * lane + 0][wd] = a0;
      Dbits[4 * lane + 1][wd] = a1;
      Dbits[4 * lane + 2][wd] = a2;
      Dbits[4 * lane + 3][wd] = a3;
    }
    __builtin_amdgcn_s_waitcnt(WAIT_LGKM0);  // drain own-wave LDS writes

    // -------- literal backtrack [validated R2-R6] --------
    if (lane == 0) {
      int* pb = pathg + b * TLEN;
      int r = tl - 1;
      pb[ml - 1] = r;
      int curR = 1 << 30, curW = -1;
      uint32_t W = 0;
      for (int qq = ml - 2; qq >= 0; --qq) {
        int w2 = qq >> 5;
        if (r >= 0 && (r != curR || w2 != curW)) { W = Dbits[r][w2]; curR = r; curW = w2; }
        int g = (r >= 0) ? (int)((W >> (qq & 31)) & 1u) : 0;
        r -= g;
        pb[qq] = r;
      }
    }
  }
}

// ---------------------------------------------------------------------------
// K3: zero alignment region (held lo-scratch) + scatter one-hots [validated]
// ---------------------------------------------------------------------------
__global__ __launch_bounds__(256) void finalize_kernel(
    const int* __restrict__ mlen, const int* __restrict__ pathg,
    float* __restrict__ out) {
  int b = blockIdx.y;
  int t0 = blockIdx.x * 8;
  float* al = out + OFF_ALIGN + (size_t)b * TLEN * LLEN;
  float4 z4 = make_float4(0.f, 0.f, 0.f, 0.f);
  #pragma unroll
  for (int p = 0; p < 2; ++p) {
    int idx = p * 256 + threadIdx.x;
    int r = idx >> 6, c4 = idx & 63;
    *(float4*)(al + (size_t)(t0 + r) * LLEN + c4 * 4) = z4;
  }
  __syncthreads();
  if (threadIdx.x < 8) {
    int t = t0 + threadIdx.x;
    int ml = mlen[b];
    if (t < ml) {
      int p = pathg[b * TLEN + t];
      if (p >= 0) al[(size_t)t * LLEN + p] = 1.0f;
    }
  }
}

extern "C" void kernel_launch(void* const* d_in, const int* in_sizes, int n_in,
                              void* d_out, int out_size, void* d_ws, size_t ws_size,
                              hipStream_t stream) {
  const float* mu_logvar = (const float*)d_in[0];
  const float* z         = (const float*)d_in[1];
  const int*   tlv       = (const int*)d_in[2];
  const int*   mlv       = (const int*)d_in[3];
  float* out = (float*)d_out;
  char*  wsb = (char*)d_ws;

  double* Ad   = (double*)(wsb + WSB_A);
  double* Kcd  = (double*)(wsb + WSB_KC);
  float*  lpTh = (float*)(wsb + WSB_LPT);
  int*    path = (int*)(wsb + WSB_PATH);

  prep_kernel<<<dim3(BB * LLEN / 4), 256, 0, stream>>>(mu_logvar, Ad, Kcd);
  lp_kernel<<<dim3(13, 8, BB), 128, 0, stream>>>(z, Ad, Kcd, out, lpTh);
  dp_kernel<<<dim3(2 * BB), 320, 0, stream>>>(lpTh, out, tlv, mlv, out, path);
  finalize_kernel<<<dim3(TLEN / 8, BB), 256, 0, stream>>>(mlv, path, out);
}